// Round 13
// baseline (232.371 us; speedup 1.0000x reference)
//
#include <hip/hip_runtime.h>
#include <hip/hip_bf16.h>

namespace {

constexpr int kN  = 1024;
constexpr int kU  = 64;

typedef __attribute__((ext_vector_type(4))) float f32x4;
typedef __attribute__((ext_vector_type(8))) short sv8;
typedef unsigned int u32;
typedef unsigned short u16;

__device__ __forceinline__ u32 pack_bf2(float a, float b) {
  __hip_bfloat16 ha = __float2bfloat16(a);
  __hip_bfloat16 hb = __float2bfloat16(b);
  u16 ua = *reinterpret_cast<u16*>(&ha);
  u16 ub = *reinterpret_cast<u16*>(&hb);
  return (u32)ua | ((u32)ub << 16);
}

__device__ __forceinline__ u16 bf16bits(float a) {
  __hip_bfloat16 h = __float2bfloat16(a);
  return *reinterpret_cast<u16*>(&h);
}

__device__ __forceinline__ float bfu(u16 v) {
  u32 x = (u32)v << 16;
  return *reinterpret_cast<float*>(&x);
}

__device__ __forceinline__ float bflo(u32 v) {
  u32 x = v << 16;
  return *reinterpret_cast<float*>(&x);
}
__device__ __forceinline__ float bfhi(u32 v) {
  u32 x = v & 0xffff0000u;
  return *reinterpret_cast<float*>(&x);
}

// ---------------------------------------------------------------------------
// K0: supports f32 -> TILED bf16 layout (einsum-native). VERBATIM from R12
// (verified passing). supb[(b*16+tile)*2+s] = 128 KB region of 16 T-chunks
// (8 KB each), chunk = [ks(2)][ih(4)][lane(64)][8 bf16].
// ---------------------------------------------------------------------------
__global__ __launch_bounds__(256) void convert_sup(
    const f32x4* __restrict__ sup4, u16* __restrict__ supb) {
  const int bx = blockIdx.x;
  const int b  = bx >> 6;
  const int rg = bx & 63;
  const int tile = rg >> 2, w = rg & 3;
  const int t  = threadIdx.x;
  const int l64 = t & 63, tg = t >> 6;
  const int T2 = l64 >> 5, ks = (l64 >> 4) & 1, q = (l64 >> 2) & 3;
  const int e  = (l64 & 3) * 2;

  __shared__ u16 CL[4096];  // 8 KB: [s(2)][T2(2)][ks(2)][lm(16)][q(4)][e(8)]

  const size_t rowbase = (size_t)(b * 1024 + rg * 16) * 512;  // f32x4 units
  u16* const outbase =
      supb + ((size_t)((b * 16 + tile) * 2)) * 65536 + w * 512;

#pragma unroll 1
  for (int jc = 0; jc < 8; ++jc) {
    f32x4 v0 = __builtin_nontemporal_load(sup4 + rowbase + (size_t)(tg) * 512 + jc * 64 + l64);
    f32x4 v1 = __builtin_nontemporal_load(sup4 + rowbase + (size_t)(tg + 4) * 512 + jc * 64 + l64);
    f32x4 v2 = __builtin_nontemporal_load(sup4 + rowbase + (size_t)(tg + 8) * 512 + jc * 64 + l64);
    f32x4 v3 = __builtin_nontemporal_load(sup4 + rowbase + (size_t)(tg + 12) * 512 + jc * 64 + l64);
    const int ob = T2 * 1024 + ks * 512 + q * 8 + e;
    *reinterpret_cast<u32*>(&CL[ob + (tg) * 32])            = pack_bf2(v0[0], v0[2]);
    *reinterpret_cast<u32*>(&CL[2048 + ob + (tg) * 32])     = pack_bf2(v0[1], v0[3]);
    *reinterpret_cast<u32*>(&CL[ob + (tg + 4) * 32])        = pack_bf2(v1[0], v1[2]);
    *reinterpret_cast<u32*>(&CL[2048 + ob + (tg + 4) * 32]) = pack_bf2(v1[1], v1[3]);
    *reinterpret_cast<u32*>(&CL[ob + (tg + 8) * 32])        = pack_bf2(v2[0], v2[2]);
    *reinterpret_cast<u32*>(&CL[2048 + ob + (tg + 8) * 32]) = pack_bf2(v2[1], v2[3]);
    *reinterpret_cast<u32*>(&CL[ob + (tg + 12) * 32])       = pack_bf2(v3[0], v3[2]);
    *reinterpret_cast<u32*>(&CL[2048 + ob + (tg + 12) * 32])= pack_bf2(v3[1], v3[3]);
    __syncthreads();
#pragma unroll
    for (int pi2 = 0; pi2 < 2; ++pi2) {
      int pi = tg + pi2 * 4;             // 0..7 = [s][T2o][kso]
      int so = pi >> 2, T2o = (pi >> 1) & 1, kso = pi & 1;
      uint4 d = *reinterpret_cast<const uint4*>(
          &CL[so * 2048 + T2o * 1024 + kso * 512 + (l64 & 15) * 32 + (l64 >> 4) * 8]);
      u16* dst = outbase + (size_t)so * 65536 + (jc * 2 + T2o) * 4096 +
                 kso * 2048 + (size_t)l64 * 8;
      *reinterpret_cast<uint4*>(dst) = d;
    }
    __syncthreads();
  }
}

// ---------------------------------------------------------------------------
// K1: build TILED x0 buffers. xt (pass 1): f=0,1 inputs, f=2..65 h_prev,
// f=66..79 zero. xtc (pass 2): inputs + zeros only (state rows written by
// gates_ru). Tiled element (f, j=T*64+ks*32+q*8+e) lives at
// chunk(b,T) + (ks*5 + f/16)*512 + (q*16 + f%16)*8 + e.
// ---------------------------------------------------------------------------
__global__ __launch_bounds__(256) void build_x0t(
    const float* __restrict__ inputs, const float* __restrict__ h_prev,
    u16* __restrict__ xt, u16* __restrict__ xtc) {
  const int bx = blockIdx.x;
  const int b  = bx >> 4;
  const int T  = bx & 15;
  const int n0 = T * 64;
  const int t  = threadIdx.x;

  __shared__ float hp[64][65];

  const float* hpg = h_prev + (size_t)b * kN * kU + (size_t)n0 * kU;
#pragma unroll
  for (int r = 0; r < 16; ++r) {
    int idx = t + (r << 8);
    hp[idx >> 6][idx & 63] = hpg[idx];
  }
  __syncthreads();

  u16* xtb  = xt  + ((size_t)(b * 16 + T) * 10) * 512;
  u16* xtcb = xtc + ((size_t)(b * 16 + T) * 10) * 512;

#pragma unroll 1
  for (int idx = t; idx < 5120; idx += 256) {
    int f = idx >> 6, j = idx & 63;
    int ks = j >> 5, qq = (j >> 3) & 3, e = j & 7;
    int off = (ks * 5 + (f >> 4)) * 512 + (qq * 16 + (f & 15)) * 8 + e;
    u16 v;
    if (f < 2)       v = bf16bits(inputs[((size_t)(b << 10) + n0 + j) * 2 + f]);
    else if (f < 66) v = bf16bits(hp[j][f - 2]);
    else             v = 0;
    xtb[off] = v;
    if (f < 2)        xtcb[off] = v;
    else if (f >= 66) xtcb[off] = 0;
  }
}

// ---------------------------------------------------------------------------
// K2/K4: graph-diffusion einsum — REGISTER-DIRECT, no LDS / no barriers in
// the K-loop (convert-isomorphic). Block = (b, tile, s), 4 waves = ih.
// Per T: 2 coalesced A-loads (1 KB/wave) straight into MFMA a-operands,
// 10 coalesced X-loads (L2-hot), 10 MFMAs. TLP (16 waves/CU) hides latency.
// ---------------------------------------------------------------------------
__global__ __launch_bounds__(256, 4) void einsum_diff(
    const u16* __restrict__ supb, const u16* __restrict__ xt,
    u16* __restrict__ xfeat) {
  const int bx = blockIdx.x;
  const int wk = (bx & 7) * 128 + (bx >> 3);  // XCD-chunked bijective (8*128)
  const int b    = wk >> 5;
  const int rem  = wk & 31;
  const int tile = rem >> 1;
  const int s    = rem & 1;
  const int i0   = tile * 64;
  const int t    = threadIdx.x;
  const int lane = t & 63;
  const int w    = t >> 6;     // ih 0..3
  const int q    = lane >> 4;
  const int lm   = lane & 15;

  __shared__ u16 ep[64][68];   // epilogue transpose only

  f32x4 acc[5];
#pragma unroll
  for (int n = 0; n < 5; ++n) acc[n] = (f32x4){0.f, 0.f, 0.f, 0.f};

  const u16* asrc = supb + ((size_t)((b * 16 + tile) * 2 + s)) * 65536 +
                    w * 512 + (size_t)lane * 8;
  const u16* xb = xt + (size_t)(b * 16) * 5120 + (size_t)lane * 8;

#pragma unroll 1
  for (int T = 0; T < 16; ++T) {
    sv8 a0 = *reinterpret_cast<const sv8*>(asrc + T * 4096);
    sv8 a1 = *reinterpret_cast<const sv8*>(asrc + T * 4096 + 2048);
    sv8 X[10];
#pragma unroll
    for (int seg = 0; seg < 10; ++seg)
      X[seg] = *reinterpret_cast<const sv8*>(xb + T * 5120 + seg * 512);
#pragma unroll
    for (int n = 0; n < 5; ++n)
      acc[n] = __builtin_amdgcn_mfma_f32_16x16x32_bf16(a0, X[n], acc[n], 0, 0, 0);
#pragma unroll
    for (int n = 0; n < 5; ++n)
      acc[n] = __builtin_amdgcn_mfma_f32_16x16x32_bf16(a1, X[5 + n], acc[n], 0, 0, 0);
  }

  // ---- epilogue: acc -> LDS bf16 [64][68] -> coalesced global (R11) ----
#pragma unroll
  for (int n = 0; n < 5; ++n) {
    int f = n * 16 + lm;
    if (f < 66) {
#pragma unroll
      for (int r = 0; r < 4; ++r)
        ep[w * 16 + q * 4 + r][f] = bf16bits(acc[n][r]);
    }
  }
  __syncthreads();
  const u32* ep32 = reinterpret_cast<const u32*>(&ep[0][0]);  // [64][34]
  u32* og = reinterpret_cast<u32*>(xfeat) + ((size_t)b * kN + i0) * 66 + s * 33;
#pragma unroll 1
  for (int g = t; g < 2112; g += 256) {   // 64 rows x 33 u32
    int row = g / 33, c = g - row * 33;
    og[(size_t)row * 66 + c] = ep32[row * 34 + c];
  }
}

// ---------------------------------------------------------------------------
// K3: r/u gates. Writes u_buf (f32), rh (bf16, coalesced) and scatters
// bf16(r*h) into the TILED xtc state rows.
// ---------------------------------------------------------------------------
__global__ __launch_bounds__(256) void gates_ru(
    const u16* __restrict__ xfeat, const float* __restrict__ rk,
    const float* __restrict__ rbias, const float* __restrict__ uk,
    const float* __restrict__ ubias, const float* __restrict__ inputs,
    const float* __restrict__ h_prev, float* __restrict__ u_buf,
    u16* __restrict__ xtc, u16* __restrict__ rh) {
  const int row0 = blockIdx.x * 32;
  const int b = row0 >> 10, n0 = row0 & 1023;
  const int t = threadIdx.x;
  __shared__ float xm[32][134];
  __shared__ float x0s[32][66];

  {
    const u32* xsrc = reinterpret_cast<const u32*>(xfeat) + (size_t)row0 * 66;
#pragma unroll 1
    for (int g = t; g < 2112; g += 256) {
      int row = g / 66, c = g - row * 66;
      u32 v = xsrc[g];
      xm[row][c * 2]     = bflo(v);
      xm[row][c * 2 + 1] = bfhi(v);
    }
  }
#pragma unroll
  for (int r2 = 0; r2 < 8; ++r2) {
    int idx = t + (r2 << 8);
    int rw = idx >> 6, u = idx & 63;
    x0s[rw][2 + u] = h_prev[(size_t)(row0 + rw) * kU + u];
  }
  if (t < 64) x0s[t >> 1][t & 1] = inputs[(size_t)row0 * 2 + t];
  __syncthreads();

  const int cu = t & 15;
  const int rw = (t >> 4) * 2;
  float ar[2][4] = {{0.f,0.f,0.f,0.f},{0.f,0.f,0.f,0.f}};
  float au[2][4] = {{0.f,0.f,0.f,0.f},{0.f,0.f,0.f,0.f}};

#pragma unroll 4
  for (int f = 0; f < 66; ++f) {  // m = 0
    float4 vr = *reinterpret_cast<const float4*>(rk + (size_t)(f * 3) * kU + cu * 4);
    float4 vu = *reinterpret_cast<const float4*>(uk + (size_t)(f * 3) * kU + cu * 4);
    float a0 = x0s[rw][f], a1 = x0s[rw + 1][f];
    ar[0][0] += a0 * vr.x; ar[0][1] += a0 * vr.y; ar[0][2] += a0 * vr.z; ar[0][3] += a0 * vr.w;
    ar[1][0] += a1 * vr.x; ar[1][1] += a1 * vr.y; ar[1][2] += a1 * vr.z; ar[1][3] += a1 * vr.w;
    au[0][0] += a0 * vu.x; au[0][1] += a0 * vu.y; au[0][2] += a0 * vu.z; au[0][3] += a0 * vu.w;
    au[1][0] += a1 * vu.x; au[1][1] += a1 * vu.y; au[1][2] += a1 * vu.z; au[1][3] += a1 * vu.w;
  }
#pragma unroll
  for (int m = 1; m <= 2; ++m) {
#pragma unroll 4
    for (int f = 0; f < 66; ++f) {
      float4 vr = *reinterpret_cast<const float4*>(rk + (size_t)(f * 3 + m) * kU + cu * 4);
      float4 vu = *reinterpret_cast<const float4*>(uk + (size_t)(f * 3 + m) * kU + cu * 4);
      float a0 = xm[rw][(m - 1) * 66 + f], a1 = xm[rw + 1][(m - 1) * 66 + f];
      ar[0][0] += a0 * vr.x; ar[0][1] += a0 * vr.y; ar[0][2] += a0 * vr.z; ar[0][3] += a0 * vr.w;
      ar[1][0] += a1 * vr.x; ar[1][1] += a1 * vr.y; ar[1][2] += a1 * vr.z; ar[1][3] += a1 * vr.w;
      au[0][0] += a0 * vu.x; au[0][1] += a0 * vu.y; au[0][2] += a0 * vu.z; au[0][3] += a0 * vu.w;
      au[1][0] += a1 * vu.x; au[1][1] += a1 * vu.y; au[1][2] += a1 * vu.z; au[1][3] += a1 * vu.w;
    }
  }

#pragma unroll
  for (int rr = 0; rr < 2; ++rr) {
    int grow = row0 + rw + rr;
    int n = n0 + rw + rr;
    int T = n >> 6, j = n & 63;
    int ks = j >> 5, qq = (j >> 3) & 3, e = j & 7;
    size_t chunk = ((size_t)(b * 16 + T) * 10) * 512;
#pragma unroll
    for (int jj = 0; jj < 4; ++jj) {
      int u = cu * 4 + jj;
      float rv = 1.f / (1.f + __expf(-(ar[rr][jj] + rbias[u])));
      float uv = 1.f / (1.f + __expf(-(au[rr][jj] + ubias[u])));
      u_buf[(size_t)grow * kU + u] = uv;
      float rhv = rv * h_prev[(size_t)grow * kU + u];
      u16 rb16 = bf16bits(rhv);
      rh[(size_t)grow * kU + u] = rb16;
      int f = 2 + u;
      xtc[chunk + (size_t)((ks * 5 + (f >> 4)) * 512 +
                           (qq * 16 + (f & 15)) * 8 + e)] = rb16;
    }
  }
}

// ---------------------------------------------------------------------------
// K5: c gate + GRU update. m0 state term from compact rh buffer (coalesced).
// ---------------------------------------------------------------------------
__global__ __launch_bounds__(256) void gate_c_final(
    const u16* __restrict__ xfeat, const float* __restrict__ ck,
    const float* __restrict__ cbias, const float* __restrict__ inputs,
    const u16* __restrict__ rh, const float* __restrict__ h_prev,
    const float* __restrict__ u_buf, float* __restrict__ out) {
  const int row0 = blockIdx.x * 32;
  const int t = threadIdx.x;
  __shared__ float xm[32][134];
  __shared__ float x0c[32][66];

  {
    const u32* xsrc = reinterpret_cast<const u32*>(xfeat) + (size_t)row0 * 66;
#pragma unroll 1
    for (int g = t; g < 2112; g += 256) {
      int row = g / 66, c = g - row * 66;
      u32 v = xsrc[g];
      xm[row][c * 2]     = bflo(v);
      xm[row][c * 2 + 1] = bfhi(v);
    }
  }
#pragma unroll
  for (int r2 = 0; r2 < 8; ++r2) {
    int idx = t + (r2 << 8);
    int rw2 = idx >> 6, u = idx & 63;
    x0c[rw2][2 + u] = bfu(rh[(size_t)(row0 + rw2) * kU + u]);
  }
  if (t < 64) x0c[t >> 1][t & 1] = inputs[(size_t)row0 * 2 + t];
  __syncthreads();

  const int cu = t & 15;
  const int rw = (t >> 4) * 2;
  float ac[2][4] = {{0.f,0.f,0.f,0.f},{0.f,0.f,0.f,0.f}};

#pragma unroll 4
  for (int f = 0; f < 66; ++f) {  // m = 0
    float4 vc = *reinterpret_cast<const float4*>(ck + (size_t)(f * 3) * kU + cu * 4);
    float a0 = x0c[rw][f], a1 = x0c[rw + 1][f];
    ac[0][0] += a0 * vc.x; ac[0][1] += a0 * vc.y; ac[0][2] += a0 * vc.z; ac[0][3] += a0 * vc.w;
    ac[1][0] += a1 * vc.x; ac[1][1] += a1 * vc.y; ac[1][2] += a1 * vc.z; ac[1][3] += a1 * vc.w;
  }
#pragma unroll
  for (int m = 1; m <= 2; ++m) {
#pragma unroll 4
    for (int f = 0; f < 66; ++f) {
      float4 vc = *reinterpret_cast<const float4*>(ck + (size_t)(f * 3 + m) * kU + cu * 4);
      float a0 = xm[rw][(m - 1) * 66 + f], a1 = xm[rw + 1][(m - 1) * 66 + f];
      ac[0][0] += a0 * vc.x; ac[0][1] += a0 * vc.y; ac[0][2] += a0 * vc.z; ac[0][3] += a0 * vc.w;
      ac[1][0] += a1 * vc.x; ac[1][1] += a1 * vc.y; ac[1][2] += a1 * vc.z; ac[1][3] += a1 * vc.w;
    }
  }

#pragma unroll
  for (int rr = 0; rr < 2; ++rr) {
    int grow = row0 + rw + rr;
#pragma unroll
    for (int j = 0; j < 4; ++j) {
      int u = cu * 4 + j;
      float cv = tanhf(ac[rr][j] + cbias[u]);
      float uv = u_buf[(size_t)grow * kU + u];
      float hp = h_prev[(size_t)grow * kU + u];
      out[(size_t)grow * kU + u] = uv * hp + (1.f - uv) * cv;
    }
  }
}

}  // namespace

extern "C" void kernel_launch(void* const* d_in, const int* in_sizes, int n_in,
                              void* d_out, int out_size, void* d_ws, size_t ws_size,
                              hipStream_t stream) {
  const float* inputs = (const float*)d_in[0];
  const float* sup    = (const float*)d_in[1];
  const float* h_prev = (const float*)d_in[2];
  const float* rk     = (const float*)d_in[3];
  const float* rbias  = (const float*)d_in[4];
  const float* uk     = (const float*)d_in[5];
  const float* ubias  = (const float*)d_in[6];
  const float* ck     = (const float*)d_in[7];
  const float* cbias  = (const float*)d_in[8];
  float* out = (float*)d_out;

  char* ws = (char*)d_ws;
  u16*   xt    = (u16*)(ws);                           //   5,242,880 B
  u16*   xtc   = (u16*)(ws + 5242880);                 //   5,242,880 B
  u16*   xfeat = (u16*)(ws + 10485760);                //   8,650,752 B
  float* u_buf = (float*)(ws + 19136512);              //   8,388,608 B
  u16*   rh    = (u16*)(ws + 27525120);                //   4,194,304 B
  u16*   supb  = (u16*)(ws + 31719424);                // 134,217,728 B

  hipLaunchKernelGGL(convert_sup, dim3(2048), dim3(256), 0, stream,
                     (const f32x4*)sup, supb);
  hipLaunchKernelGGL(build_x0t, dim3(512), dim3(256), 0, stream,
                     inputs, h_prev, xt, xtc);
  hipLaunchKernelGGL(einsum_diff, dim3(1024), dim3(256), 0, stream,
                     supb, xt, xfeat);
  hipLaunchKernelGGL(gates_ru, dim3(1024), dim3(256), 0, stream,
                     xfeat, rk, rbias, uk, ubias, inputs, h_prev, u_buf, xtc, rh);
  hipLaunchKernelGGL(einsum_diff, dim3(1024), dim3(256), 0, stream,
                     supb, xtc, xfeat);
  hipLaunchKernelGGL(gate_c_final, dim3(1024), dim3(256), 0, stream,
                     xfeat, ck, cbias, inputs, rh, h_prev, u_buf, out);
}

// Round 14
// 213.130 us; speedup vs baseline: 1.0903x; 1.0903x over previous
//
#include <hip/hip_runtime.h>
#include <hip/hip_bf16.h>

namespace {

constexpr int kN  = 1024;
constexpr int kU  = 64;
constexpr int kFP = 80;   // padded feature dim (5 tiles of 16)

typedef __attribute__((ext_vector_type(4))) float f32x4;
typedef __attribute__((ext_vector_type(8))) short sv8;
typedef unsigned int u32;
typedef unsigned short u16;

__device__ __forceinline__ u32 pack_bf2(float a, float b) {
  __hip_bfloat16 ha = __float2bfloat16(a);
  __hip_bfloat16 hb = __float2bfloat16(b);
  u16 ua = *reinterpret_cast<u16*>(&ha);
  u16 ub = *reinterpret_cast<u16*>(&hb);
  return (u32)ua | ((u32)ub << 16);
}

__device__ __forceinline__ u16 bf16bits(float a) {
  __hip_bfloat16 h = __float2bfloat16(a);
  return *reinterpret_cast<u16*>(&h);
}

__device__ __forceinline__ float bflo(u32 v) {
  u32 x = v << 16;
  return *reinterpret_cast<float*>(&x);
}
__device__ __forceinline__ float bfhi(u32 v) {
  u32 x = v & 0xffff0000u;
  return *reinterpret_cast<float*>(&x);
}

__device__ __forceinline__ void gl16(const void* g, void* l) {
  __builtin_amdgcn_global_load_lds(
      (const __attribute__((address_space(1))) u32*)g,
      (__attribute__((address_space(3))) u32*)l, 16, 0, 0);
}

// ---------------------------------------------------------------------------
// K0: supports f32 -> TILED bf16, INTERLEAVED chunk order.
// Chunk address = (T*1024 + region)*4096 u16, region=(b*16+tile)*2+s in
// [0,1024) = block count. All blocks at K-step T read one dense 4 MB window.
// Chunk internals [ks][ih][lane][8] identical to R12 (verified).
// ---------------------------------------------------------------------------
__global__ __launch_bounds__(256) void convert_sup(
    const f32x4* __restrict__ sup4, u16* __restrict__ supb) {
  const int bx = blockIdx.x;
  const int b  = bx >> 6;
  const int rg = bx & 63;
  const int tile = rg >> 2, w = rg & 3;
  const int t  = threadIdx.x;
  const int l64 = t & 63, tg = t >> 6;
  const int T2 = l64 >> 5, ks = (l64 >> 4) & 1, q = (l64 >> 2) & 3;
  const int e  = (l64 & 3) * 2;

  __shared__ u16 CL[4096];  // 8 KB: [s(2)][T2(2)][ks(2)][lm(16)][q(4)][e(8)]

  const size_t rowbase = (size_t)(b * 1024 + rg * 16) * 512;  // f32x4 units
  const int region0 = (b * 16 + tile) * 2;

#pragma unroll 1
  for (int jc = 0; jc < 8; ++jc) {
    f32x4 v0 = __builtin_nontemporal_load(sup4 + rowbase + (size_t)(tg) * 512 + jc * 64 + l64);
    f32x4 v1 = __builtin_nontemporal_load(sup4 + rowbase + (size_t)(tg + 4) * 512 + jc * 64 + l64);
    f32x4 v2 = __builtin_nontemporal_load(sup4 + rowbase + (size_t)(tg + 8) * 512 + jc * 64 + l64);
    f32x4 v3 = __builtin_nontemporal_load(sup4 + rowbase + (size_t)(tg + 12) * 512 + jc * 64 + l64);
    const int ob = T2 * 1024 + ks * 512 + q * 8 + e;
    *reinterpret_cast<u32*>(&CL[ob + (tg) * 32])            = pack_bf2(v0[0], v0[2]);
    *reinterpret_cast<u32*>(&CL[2048 + ob + (tg) * 32])     = pack_bf2(v0[1], v0[3]);
    *reinterpret_cast<u32*>(&CL[ob + (tg + 4) * 32])        = pack_bf2(v1[0], v1[2]);
    *reinterpret_cast<u32*>(&CL[2048 + ob + (tg + 4) * 32]) = pack_bf2(v1[1], v1[3]);
    *reinterpret_cast<u32*>(&CL[ob + (tg + 8) * 32])        = pack_bf2(v2[0], v2[2]);
    *reinterpret_cast<u32*>(&CL[2048 + ob + (tg + 8) * 32]) = pack_bf2(v2[1], v2[3]);
    *reinterpret_cast<u32*>(&CL[ob + (tg + 12) * 32])       = pack_bf2(v3[0], v3[2]);
    *reinterpret_cast<u32*>(&CL[2048 + ob + (tg + 12) * 32])= pack_bf2(v3[1], v3[3]);
    __syncthreads();
#pragma unroll
    for (int pi2 = 0; pi2 < 2; ++pi2) {
      int pi = tg + pi2 * 4;             // 0..7 = [s][T2o][kso]
      int so = pi >> 2, T2o = (pi >> 1) & 1, kso = pi & 1;
      uint4 d = *reinterpret_cast<const uint4*>(
          &CL[so * 2048 + T2o * 1024 + kso * 512 + (l64 & 15) * 32 + (l64 >> 4) * 8]);
      int T = jc * 2 + T2o;
      u16* dst = supb + ((size_t)T * 1024 + region0 + so) * 4096 +
                 kso * 2048 + w * 512 + (size_t)l64 * 8;
      *reinterpret_cast<uint4*>(dst) = d;
    }
    __syncthreads();
  }
}

// ---------------------------------------------------------------------------
// K1: build x0^T bf16 (B, 80, 1024).  (verbatim R12)
// ---------------------------------------------------------------------------
__global__ __launch_bounds__(256) void build_x0t(
    const float* __restrict__ inputs, const float* __restrict__ h_prev,
    __hip_bfloat16* __restrict__ x0t, __hip_bfloat16* __restrict__ x0tc) {
  const int bx = blockIdx.x;
  const int b  = bx >> 4;
  const int n0 = (bx & 15) * 64;
  const int t  = threadIdx.x;

  __shared__ float hp[64][65];

  const float* hpg = h_prev + (size_t)b * kN * kU + (size_t)n0 * kU;
#pragma unroll
  for (int r = 0; r < 16; ++r) {
    int idx = t + (r << 8);
    hp[idx >> 6][idx & 63] = hpg[idx];
  }
  __syncthreads();

  {
    int u = t >> 2, g = t & 3;
    __hip_bfloat16* dst = x0t + ((size_t)b * kFP + 2 + u) * kN + n0 + g * 16;
#pragma unroll
    for (int k = 0; k < 16; ++k) dst[k] = __float2bfloat16(hp[g * 16 + k][u]);
  }

  if (t < 128) {
    int d = t & 1, nn = t >> 1;
    float v = inputs[((size_t)b * kN + n0 + nn) * 2 + d];
    __hip_bfloat16 bv = __float2bfloat16(v);
    x0t [((size_t)b * kFP + d) * kN + n0 + nn] = bv;
    x0tc[((size_t)b * kFP + d) * kN + n0 + nn] = bv;
  } else {
    int i2 = t - 128;
    __hip_bfloat16 z = __float2bfloat16(0.0f);
#pragma unroll
    for (int r = 0; r < 7; ++r) {
      int idx = i2 + r * 128;
      int row = 66 + (idx >> 6), nn = idx & 63;
      x0t [((size_t)b * kFP + row) * kN + n0 + nn] = z;
      x0tc[((size_t)b * kFP + row) * kN + n0 + nn] = z;
    }
  }
}

// ---------------------------------------------------------------------------
// K2/K4: graph-diffusion einsum (R12 structure verbatim; only the A-chunk
// address map changed to the interleaved [T][region] order). Double-buffered
// 52 KB LDS, depth-1 counted vmcnt, 2 raw barriers/iter (race-audited, R12).
// ---------------------------------------------------------------------------
__global__ __launch_bounds__(512) void einsum_diff(
    const u16* __restrict__ supb, const __hip_bfloat16* __restrict__ x0t,
    u16* __restrict__ xfeat) {
  const int bx = blockIdx.x;
  const int wk = (bx & 7) * 64 + (bx >> 3);  // XCD-chunked bijective (8*64)
  const int b    = wk >> 4;
  const int tile = wk & 15;
  const int i0   = tile * 64;
  const int t    = threadIdx.x;
  const int lane = t & 63;
  const int ww   = t >> 6;     // 0..7
  const int q    = lane >> 4;
  const int lm   = lane & 15;
  const int s    = ww & 1;
  const int ih   = ww >> 1;    // 0..3

  __shared__ u16 Af[2][2][2][4][64][8];  // [buf][s][ks][ih][lane][8]  32 KB
  __shared__ u16 Xf[2][10][64][8];       // [buf][seg][lane][8]        20 KB

  f32x4 acc[5];
#pragma unroll
  for (int n = 0; n < 5; ++n) acc[n] = (f32x4){0.f, 0.f, 0.f, 0.f};

  // A: interleaved chunks — all blocks at step T read one dense 4 MB window.
  const int region = (b * 16 + tile) * 2 + s;
  const u16* asrc = supb + (size_t)region * 4096 + ih * 512 + (size_t)lane * 8;
  // X: R9/R12 seg formulas (seg = ks*5+n).
  const u16* xg = reinterpret_cast<const u16*>(x0t) + (size_t)b * kFP * kN;
  const int seg1 = ww;
  const int seg2 = ww + 8;
  const u16* xs1 =
      xg + (size_t)((seg1 % 5) * 16 + lm) * kN + (seg1 / 5) * 32 + q * 8;
  const u16* xs2 = (ww < 2)
      ? xg + (size_t)((seg2 % 5) * 16 + lm) * kN + (seg2 / 5) * 32 + q * 8
      : nullptr;

  auto dma = [&](int nb, int T) {
    gl16(asrc + (size_t)T * 4194304,        &Af[nb][s][0][ih][0][0]);
    gl16(asrc + (size_t)T * 4194304 + 2048, &Af[nb][s][1][ih][0][0]);
    gl16(xs1 + T * 64, &Xf[nb][seg1][0][0]);
    if (ww < 2) gl16(xs2 + T * 64, &Xf[nb][seg2][0][0]);
  };

  auto compute = [&](int nb) {
#pragma unroll
    for (int ks = 0; ks < 2; ++ks) {
      sv8 a = *reinterpret_cast<const sv8*>(&Af[nb][s][ks][ih][lane][0]);
#pragma unroll
      for (int n = 0; n < 5; ++n) {
        sv8 xb = *reinterpret_cast<const sv8*>(&Xf[nb][ks * 5 + n][lane][0]);
        acc[n] = __builtin_amdgcn_mfma_f32_16x16x32_bf16(a, xb, acc[n], 0, 0, 0);
      }
    }
  };

  // prologue: batch 0 staged & visible
  dma(0, 0);
  asm volatile("s_waitcnt vmcnt(0)" ::: "memory");
  __builtin_amdgcn_s_barrier();
  __builtin_amdgcn_sched_barrier(0);

#pragma unroll 1
  for (int T = 0; T < 16; ++T) {
    if (T + 1 <= 15) {
      dma((T + 1) & 1, T + 1);   // buf (T+1)&1: prior reader compute(T-1)
                                 // is behind STEP(T-1)'s trailing barrier.
      if (ww < 2) { asm volatile("s_waitcnt vmcnt(4)" ::: "memory"); }
      else        { asm volatile("s_waitcnt vmcnt(3)" ::: "memory"); }
    } else {
      asm volatile("s_waitcnt vmcnt(0)" ::: "memory");
    }
    __builtin_amdgcn_s_barrier();        // all waves: batch T landed
    __builtin_amdgcn_sched_barrier(0);
    compute(T & 1);
    __builtin_amdgcn_s_barrier();        // reads done before next overwrite
    __builtin_amdgcn_sched_barrier(0);
  }

  // ---- epilogue: acc -> LDS bf16 [64][136] -> coalesced global ----
  u16* ep = &Af[0][0][0][0][0][0];
#pragma unroll
  for (int n = 0; n < 5; ++n) {
    int f = n * 16 + lm;
    if (f < 66) {
#pragma unroll
      for (int r = 0; r < 4; ++r) {
        int row = ih * 16 + q * 4 + r;
        ep[row * 136 + s * 66 + f] = bf16bits(acc[n][r]);
      }
    }
  }
  __syncthreads();
  const u32* ep32 = reinterpret_cast<const u32*>(ep);  // [64][68]
  u32* og = reinterpret_cast<u32*>(xfeat) + ((size_t)b * kN + i0) * 66;
#pragma unroll 1
  for (int g = t; g < 4224; g += 512) {
    int row = g / 66, c = g - row * 66;
    og[g] = ep32[row * 68 + c];
  }
}

// ---------------------------------------------------------------------------
// K3: r/u gates (xfeat bf16).  (verbatim R12)
// ---------------------------------------------------------------------------
__global__ __launch_bounds__(256) void gates_ru(
    const u16* __restrict__ xfeat, const float* __restrict__ rk,
    const float* __restrict__ rbias, const float* __restrict__ uk,
    const float* __restrict__ ubias, const float* __restrict__ inputs,
    const float* __restrict__ h_prev, float* __restrict__ u_buf,
    __hip_bfloat16* __restrict__ x0tc) {
  const int row0 = blockIdx.x * 32;
  const int b = row0 >> 10, n0 = row0 & 1023;
  const int t = threadIdx.x;
  __shared__ float xm[32][134];
  __shared__ float x0s[32][66];

  {
    const u32* xsrc = reinterpret_cast<const u32*>(xfeat) + (size_t)row0 * 66;
#pragma unroll 1
    for (int g = t; g < 2112; g += 256) {
      int row = g / 66, c = g - row * 66;
      u32 v = xsrc[g];
      xm[row][c * 2]     = bflo(v);
      xm[row][c * 2 + 1] = bfhi(v);
    }
  }
#pragma unroll
  for (int r2 = 0; r2 < 8; ++r2) {
    int idx = t + (r2 << 8);
    int rw = idx >> 6, u = idx & 63;
    x0s[rw][2 + u] = h_prev[(size_t)(row0 + rw) * kU + u];
  }
  if (t < 64) x0s[t >> 1][t & 1] = inputs[(size_t)row0 * 2 + t];
  __syncthreads();

  const int cu = t & 15;
  const int rw = (t >> 4) * 2;
  float ar[2][4] = {{0.f,0.f,0.f,0.f},{0.f,0.f,0.f,0.f}};
  float au[2][4] = {{0.f,0.f,0.f,0.f},{0.f,0.f,0.f,0.f}};

#pragma unroll 4
  for (int f = 0; f < 66; ++f) {  // m = 0
    float4 vr = *reinterpret_cast<const float4*>(rk + (size_t)(f * 3) * kU + cu * 4);
    float4 vu = *reinterpret_cast<const float4*>(uk + (size_t)(f * 3) * kU + cu * 4);
    float a0 = x0s[rw][f], a1 = x0s[rw + 1][f];
    ar[0][0] += a0 * vr.x; ar[0][1] += a0 * vr.y; ar[0][2] += a0 * vr.z; ar[0][3] += a0 * vr.w;
    ar[1][0] += a1 * vr.x; ar[1][1] += a1 * vr.y; ar[1][2] += a1 * vr.z; ar[1][3] += a1 * vr.w;
    au[0][0] += a0 * vu.x; au[0][1] += a0 * vu.y; au[0][2] += a0 * vu.z; au[0][3] += a0 * vu.w;
    au[1][0] += a1 * vu.x; au[1][1] += a1 * vu.y; au[1][2] += a1 * vu.z; au[1][3] += a1 * vu.w;
  }
#pragma unroll
  for (int m = 1; m <= 2; ++m) {
#pragma unroll 4
    for (int f = 0; f < 66; ++f) {
      float4 vr = *reinterpret_cast<const float4*>(rk + (size_t)(f * 3 + m) * kU + cu * 4);
      float4 vu = *reinterpret_cast<const float4*>(uk + (size_t)(f * 3 + m) * kU + cu * 4);
      float a0 = xm[rw][(m - 1) * 66 + f], a1 = xm[rw + 1][(m - 1) * 66 + f];
      ar[0][0] += a0 * vr.x; ar[0][1] += a0 * vr.y; ar[0][2] += a0 * vr.z; ar[0][3] += a0 * vr.w;
      ar[1][0] += a1 * vr.x; ar[1][1] += a1 * vr.y; ar[1][2] += a1 * vr.z; ar[1][3] += a1 * vr.w;
      au[0][0] += a0 * vu.x; au[0][1] += a0 * vu.y; au[0][2] += a0 * vu.z; au[0][3] += a0 * vu.w;
      au[1][0] += a1 * vu.x; au[1][1] += a1 * vu.y; au[1][2] += a1 * vu.z; au[1][3] += a1 * vu.w;
    }
  }

#pragma unroll
  for (int rr = 0; rr < 2; ++rr) {
    int grow = row0 + rw + rr;
    int n = n0 + rw + rr;
#pragma unroll
    for (int j = 0; j < 4; ++j) {
      int u = cu * 4 + j;
      float rv = 1.f / (1.f + __expf(-(ar[rr][j] + rbias[u])));
      float uv = 1.f / (1.f + __expf(-(au[rr][j] + ubias[u])));
      u_buf[(size_t)grow * kU + u] = uv;
      float rh = rv * h_prev[(size_t)grow * kU + u];
      x0tc[((size_t)b * kFP + 2 + u) * kN + n] = __float2bfloat16(rh);
    }
  }
}

// ---------------------------------------------------------------------------
// K5: c gate + GRU update (xfeat bf16).  (verbatim R12)
// ---------------------------------------------------------------------------
__global__ __launch_bounds__(256) void gate_c_final(
    const u16* __restrict__ xfeat, const float* __restrict__ ck,
    const float* __restrict__ cbias, const float* __restrict__ inputs,
    const __hip_bfloat16* __restrict__ x0tc, const float* __restrict__ h_prev,
    const float* __restrict__ u_buf, float* __restrict__ out) {
  const int row0 = blockIdx.x * 32;
  const int b = row0 >> 10, n0 = row0 & 1023;
  const int t = threadIdx.x;
  __shared__ float xm[32][134];
  __shared__ float x0c[32][66];

  {
    const u32* xsrc = reinterpret_cast<const u32*>(xfeat) + (size_t)row0 * 66;
#pragma unroll 1
    for (int g = t; g < 2112; g += 256) {
      int row = g / 66, c = g - row * 66;
      u32 v = xsrc[g];
      xm[row][c * 2]     = bflo(v);
      xm[row][c * 2 + 1] = bfhi(v);
    }
  }
#pragma unroll
  for (int r2 = 0; r2 < 8; ++r2) {
    int idx = t + (r2 << 8);
    int u = idx >> 5, nn = idx & 31;
    x0c[nn][2 + u] =
        __bfloat162float(x0tc[((size_t)b * kFP + 2 + u) * kN + n0 + nn]);
  }
  if (t < 64) x0c[t >> 1][t & 1] = inputs[(size_t)row0 * 2 + t];
  __syncthreads();

  const int cu = t & 15;
  const int rw = (t >> 4) * 2;
  float ac[2][4] = {{0.f,0.f,0.f,0.f},{0.f,0.f,0.f,0.f}};

#pragma unroll 4
  for (int f = 0; f < 66; ++f) {  // m = 0
    float4 vc = *reinterpret_cast<const float4*>(ck + (size_t)(f * 3) * kU + cu * 4);
    float a0 = x0c[rw][f], a1 = x0c[rw + 1][f];
    ac[0][0] += a0 * vc.x; ac[0][1] += a0 * vc.y; ac[0][2] += a0 * vc.z; ac[0][3] += a0 * vc.w;
    ac[1][0] += a1 * vc.x; ac[1][1] += a1 * vc.y; ac[1][2] += a1 * vc.z; ac[1][3] += a1 * vc.w;
  }
#pragma unroll
  for (int m = 1; m <= 2; ++m) {
#pragma unroll 4
    for (int f = 0; f < 66; ++f) {
      float4 vc = *reinterpret_cast<const float4*>(ck + (size_t)(f * 3 + m) * kU + cu * 4);
      float a0 = xm[rw][(m - 1) * 66 + f], a1 = xm[rw + 1][(m - 1) * 66 + f];
      ac[0][0] += a0 * vc.x; ac[0][1] += a0 * vc.y; ac[0][2] += a0 * vc.z; ac[0][3] += a0 * vc.w;
      ac[1][0] += a1 * vc.x; ac[1][1] += a1 * vc.y; ac[1][2] += a1 * vc.z; ac[1][3] += a1 * vc.w;
    }
  }

#pragma unroll
  for (int rr = 0; rr < 2; ++rr) {
    int grow = row0 + rw + rr;
#pragma unroll
    for (int j = 0; j < 4; ++j) {
      int u = cu * 4 + j;
      float cv = tanhf(ac[rr][j] + cbias[u]);
      float uv = u_buf[(size_t)grow * kU + u];
      float hp = h_prev[(size_t)grow * kU + u];
      out[(size_t)grow * kU + u] = uv * hp + (1.f - uv) * cv;
    }
  }
}

}  // namespace

extern "C" void kernel_launch(void* const* d_in, const int* in_sizes, int n_in,
                              void* d_out, int out_size, void* d_ws, size_t ws_size,
                              hipStream_t stream) {
  const float* inputs = (const float*)d_in[0];
  const float* sup    = (const float*)d_in[1];
  const float* h_prev = (const float*)d_in[2];
  const float* rk     = (const float*)d_in[3];
  const float* rbias  = (const float*)d_in[4];
  const float* uk     = (const float*)d_in[5];
  const float* ubias  = (const float*)d_in[6];
  const float* ck     = (const float*)d_in[7];
  const float* cbias  = (const float*)d_in[8];
  float* out = (float*)d_out;

  char* ws = (char*)d_ws;
  __hip_bfloat16* x0t   = (__hip_bfloat16*)(ws);                    //  5,242,880 B
  __hip_bfloat16* x0tc  = (__hip_bfloat16*)(ws + 5242880);          //  5,242,880 B
  u16*            xfeat = (u16*)(ws + 10485760);                    //  8,650,752 B
  float*          u_buf = (float*)(ws + 19136512);                  //  8,388,608 B
  u16*            supb  = (u16*)(ws + 27525120);                    // 134,217,728 B

  hipLaunchKernelGGL(convert_sup, dim3(2048), dim3(256), 0, stream,
                     (const f32x4*)sup, supb);
  hipLaunchKernelGGL(build_x0t, dim3(512), dim3(256), 0, stream,
                     inputs, h_prev, x0t, x0tc);
  hipLaunchKernelGGL(einsum_diff, dim3(512), dim3(512), 0, stream,
                     supb, x0t, xfeat);
  hipLaunchKernelGGL(gates_ru, dim3(1024), dim3(256), 0, stream,
                     xfeat, rk, rbias, uk, ubias, inputs, h_prev, u_buf, x0tc);
  hipLaunchKernelGGL(einsum_diff, dim3(512), dim3(512), 0, stream,
                     supb, x0tc, xfeat);
  hipLaunchKernelGGL(gate_c_final, dim3(1024), dim3(256), 0, stream,
                     xfeat, ck, cbias, inputs, x0tc, h_prev, u_buf, out);
}